// Round 2
// baseline (617.528 us; speedup 1.0000x reference)
//
#include <hip/hip_runtime.h>
#include <cstdint>
#include <cmath>

typedef _Float16 half4v __attribute__((ext_vector_type(4)));
typedef _Float16 half8v __attribute__((ext_vector_type(8)));
typedef float float4v __attribute__((ext_vector_type(4)));

#define NB 16
#define NC 256
#define HW 9216   // 96*96

// ---------------------------------------------------------------------------
// Stage 1: y = dec+skip; z = 3y + w_fea*w_edge(y) + DoG(y); write f16 z in
// layout [b][c/4][hw][c%4] so the GEMM gets 4-contiguous K.
// ---------------------------------------------------------------------------
__device__ inline float bilin_lds(const float* d, int S, float srcy, float srcx) {
    float fy0 = floorf(srcy), fx0 = floorf(srcx);
    float fy = srcy - fy0, fx = srcx - fx0;
    int iy = (int)fy0, ix = (int)fx0;
    int iya = iy < 0 ? 0 : iy;
    int iyb = (iy + 1 > S - 1) ? S - 1 : iy + 1;
    int ixa = ix < 0 ? 0 : ix;
    int ixb = (ix + 1 > S - 1) ? S - 1 : ix + 1;
    float a = d[iya * S + ixa], b = d[iya * S + ixb];
    float c = d[iyb * S + ixa], e = d[iyb * S + ixb];
    float t = a + fx * (b - a);
    float u = c + fx * (e - c);
    return t + fy * (u - t);
}

__global__ __launch_bounds__(512) void stage1_kernel(
    const float* __restrict__ skip, const float* __restrict__ dec,
    const float* __restrict__ wfea, const float* __restrict__ sig1,
    const float* __restrict__ sig2, _Float16* __restrict__ zt) {
    __shared__ __align__(16) float sy[HW];          // 36864 B
    __shared__ float d72b[72 * 72];                 // 20736 B
    __shared__ float d48b[48 * 48];                 //  9216 B
    __shared__ float d24b[24 * 24];                 //  2304 B
    __shared__ __align__(16) _Float16 zb[4][HW];    // 73728 B   total 142848 B

    const int tid = threadIdx.x;
    const int b = blockIdx.x >> 6;
    const int cg = blockIdx.x & 63;

    for (int cc = 0; cc < 4; ++cc) {
        const int c = cg * 4 + cc;
        const size_t base = ((size_t)b * NC + c) * HW;
        __syncthreads();   // previous channel done reading sy/d*
        // ---- load y = dec + skip (float4) ----
        const float4* dp = (const float4*)(dec + base);
        const float4* sp = (const float4*)(skip + base);
        for (int i = tid; i < HW / 4; i += 512) {
            float4 a = dp[i], s = sp[i];
            float4 v = make_float4(a.x + s.x, a.y + s.y, a.z + s.z, a.w + s.w);
            *(float4*)&sy[i * 4] = v;
        }
        __syncthreads();
        // ---- downsamples ----
        // 96->48: src=2o+0.5 -> avg of cols/rows (2o,2o+1)
        for (int i = tid; i < 48 * 48; i += 512) {
            int oy = i / 48, ox = i - oy * 48;
            const float* r = &sy[oy * 192 + ox * 2];
            d48b[i] = 0.25f * (r[0] + r[1] + r[96] + r[97]);
        }
        // 96->24: src=4o+1.5 -> avg of (4o+1,4o+2)  [576 elems > 512 threads: LOOP]
        for (int i = tid; i < 24 * 24; i += 512) {
            int oy = i / 24, ox = i - oy * 24;
            const float* r = &sy[(4 * oy + 1) * 96 + 4 * ox + 1];
            d24b[i] = 0.25f * (r[0] + r[1] + r[96] + r[97]);
        }
        // 96->72: src=(8o+1)/6 -> i0 = 4*(o/3)+(o%3), f in {1/6,1/2,5/6}
        for (int i = tid; i < 72 * 72; i += 512) {
            int oy = i / 72, ox = i - oy * 72;
            int qy = oy / 3, ry = oy - qy * 3;
            int qx = ox / 3, rx = ox - qx * 3;
            int iy = 4 * qy + ry, ix = 4 * qx + rx;
            float fy = (ry == 0) ? 0.16666667f : (ry == 1 ? 0.5f : 0.83333333f);
            float fx = (rx == 0) ? 0.16666667f : (rx == 1 ? 0.5f : 0.83333333f);
            const float* r0 = &sy[iy * 96 + ix];
            float v0 = r0[0] + fx * (r0[1] - r0[0]);
            float v1 = r0[96] + fx * (r0[97] - r0[96]);
            d72b[i] = v0 + fy * (v1 - v0);
        }
        // ---- per-channel params ----
        float wf = wfea[c];
        float sgA = 2.f / (1.f + expf(-sig1[c]));
        float sgB = 2.f / (1.f + expf(-sig2[c]));
        float eA = expf(-0.5f / (sgA * sgA));
        float eB = expf(-0.5f / (sgB * sgB));
        float nA = 1.f + 4.f * eA + 4.f * eA * eA;
        float nB = 1.f + 4.f * eB + 4.f * eB * eB;
        float k0 = 1.f / nA - 1.f / nB;
        float k1 = eA / nA - eB / nB;
        float k2 = eA * eA / nA - eB * eB / nB;
        __syncthreads();
        // ---- per-pixel: upsample, edges, DoG, z ----
        for (int p = tid; p < HW; p += 512) {
            int h = p / 96, x = p - h * 96;
            float yv = sy[p];
            float u24 = bilin_lds(d24b, 24, h * 0.25f - 0.375f, x * 0.25f - 0.375f);
            float u48 = bilin_lds(d48b, 48, h * 0.5f - 0.25f, x * 0.5f - 0.25f);
            float u72 = bilin_lds(d72b, 72, h * 0.75f - 0.125f, x * 0.75f - 0.125f);
            float e0 = fabsf(yv - u24);
            float e1 = fabsf(yv - u48);
            float e2 = fabsf(yv - u72);
            float we = (fabsf(e0 - e1) + fabsf(e0 - e2) + fabsf(e1 - e2)) * (1.f / 3.f);
            // DoG (zero-padded 3x3, combined g1-g2 kernel: center k0, edge k1, corner k2)
            float up = (h > 0) ? sy[p - 96] : 0.f;
            float dn = (h < 95) ? sy[p + 96] : 0.f;
            float lf = (x > 0) ? sy[p - 1] : 0.f;
            float rt = (x < 95) ? sy[p + 1] : 0.f;
            float ul = (h > 0 && x > 0) ? sy[p - 97] : 0.f;
            float ur = (h > 0 && x < 95) ? sy[p - 95] : 0.f;
            float dl = (h < 95 && x > 0) ? sy[p + 95] : 0.f;
            float dr = (h < 95 && x < 95) ? sy[p + 97] : 0.f;
            float dog = k0 * yv + k1 * (up + dn + lf + rt) + k2 * (ul + ur + dl + dr);
            float z = 3.f * yv + wf * we + dog;
            zb[cc][p] = (_Float16)z;
        }
    }
    __syncthreads();
    // ---- interleaved write: [b][cg][p][4] as 8B stores ----
    _Float16* zo = zt + ((size_t)b * 64 + cg) * (size_t)HW * 4;
    for (int p = tid; p < HW; p += 512) {
        half4v v = { zb[0][p], zb[1][p], zb[2][p], zb[3][p] };
        *(half4v*)&zo[p * 4] = v;
    }
}

// ---------------------------------------------------------------------------
// Stage 2: out[b,o,n] = sum_c W[o,c] * z[b,c,n] + skip[b,o,n]
// f16 MFMA 16x16x32, BM=256 (full M), BN=128, BK=64, 512 thr = 8 waves (4m x 2n)
// ---------------------------------------------------------------------------
__global__ __launch_bounds__(512) void gemm_kernel(
    const _Float16* __restrict__ zt, const float* __restrict__ W,
    const float* __restrict__ skip, float* __restrict__ out) {
    __shared__ __align__(16) _Float16 As[256 * 72];   // W tile [m][k], pad 72
    __shared__ __align__(16) _Float16 Bs[16 * 128 * 4]; // z tile [cg][n][4]

    const int tid = threadIdx.x;
    const int ni = blockIdx.x % 72;
    const int b = blockIdx.x / 72;
    const int n0 = ni * 128;
    const int lane = tid & 63;
    const int w = tid >> 6;
    const int wm = (w & 3) * 64;
    const int wn = (w >> 2) * 64;
    const int l15 = lane & 15;
    const int quad = lane >> 4;

    float4v acc[4][4];
    for (int i = 0; i < 4; ++i)
        for (int j = 0; j < 4; ++j)
            acc[i][j] = (float4v){0.f, 0.f, 0.f, 0.f};

    for (int kt = 0; kt < 4; ++kt) {
        const int kb = kt * 64;
        __syncthreads();
        // stage A: W[0:256][kb:kb+64] f32 -> f16
        for (int p = 0; p < 8; ++p) {
            int idx = tid + p * 512;            // 0..4095
            int row = idx >> 4, c4 = (idx & 15) << 2;
            float4 wv = *(const float4*)&W[row * 256 + kb + c4];
            half4v h = { (_Float16)wv.x, (_Float16)wv.y, (_Float16)wv.z, (_Float16)wv.w };
            *(half4v*)&As[row * 72 + c4] = h;
        }
        // stage B: 16 contiguous 1KB chunks (one per c-group of 4)
        for (int p = 0; p < 2; ++p) {
            int idx = tid + p * 512;            // 0..1023
            int cgk = idx >> 6, wi = idx & 63;
            const uint4* g = (const uint4*)&zt[(((size_t)b * 64 + kt * 16 + cgk) * HW + n0) * 4 + wi * 8];
            *(uint4*)&Bs[idx * 8] = *g;
        }
        __syncthreads();
        for (int q = 0; q < 2; ++q) {
            const int kq = q * 32 + quad * 8;   // lane's k start within BK
            half8v af[4], bf[4];
            for (int i = 0; i < 4; ++i)
                af[i] = *(const half8v*)&As[(wm + i * 16 + l15) * 72 + kq];
            for (int j = 0; j < 4; ++j) {
                int nl = wn + j * 16 + l15;
                int cgk = kq >> 2;
                half4v lo = *(const half4v*)&Bs[cgk * 512 + nl * 4];
                half4v hi = *(const half4v*)&Bs[(cgk + 1) * 512 + nl * 4];
                bf[j] = __builtin_shufflevector(lo, hi, 0, 1, 2, 3, 4, 5, 6, 7);
            }
            for (int i = 0; i < 4; ++i)
                for (int j = 0; j < 4; ++j)
                    acc[i][j] = __builtin_amdgcn_mfma_f32_16x16x32_f16(af[i], bf[j], acc[i][j], 0, 0, 0);
        }
    }
    // epilogue: D row = quad*4+r, col = l15
    for (int i = 0; i < 4; ++i) {
        for (int r = 0; r < 4; ++r) {
            int o = wm + i * 16 + quad * 4 + r;
            size_t rowbase = ((size_t)b * NC + o) * HW + n0;
            for (int j = 0; j < 4; ++j) {
                int n = wn + j * 16 + l15;
                out[rowbase + n] = acc[i][j][r] + skip[rowbase + n];
            }
        }
    }
}

extern "C" void kernel_launch(void* const* d_in, const int* in_sizes, int n_in,
                              void* d_out, int out_size, void* d_ws, size_t ws_size,
                              hipStream_t stream) {
    const float* skip = (const float*)d_in[0];
    const float* dec  = (const float*)d_in[1];
    const float* wfea = (const float*)d_in[2];
    const float* sg1  = (const float*)d_in[3];
    const float* sg2  = (const float*)d_in[4];
    const float* W    = (const float*)d_in[5];
    float* out = (float*)d_out;
    _Float16* zt = (_Float16*)d_ws;   // 75.5 MB: [16][64][9216][4] f16

    stage1_kernel<<<NB * 64, 512, 0, stream>>>(skip, dec, wfea, sg1, sg2, zt);
    gemm_kernel<<<72 * NB, 512, 0, stream>>>(zt, W, skip, out);
}